// Round 9
// baseline (638.248 us; speedup 1.0000x reference)
//
#include <hip/hip_runtime.h>
#include <hip/hip_bf16.h>
#include <math.h>

#define B_    64
#define T_    256
#define EMB_  300
#define HW_   128
#define G4_   512     // 4*HW
#define P1_   46
#define NPOS  (B_*T_) // 16384

typedef short  short8 __attribute__((ext_vector_type(8)));
typedef float  f32x4  __attribute__((ext_vector_type(4)));

__device__ __forceinline__ float sigmoidf_(float x) {
  return 1.0f / (1.0f + __expf(-x));
}
__device__ __forceinline__ float ftanh_(float x) {
  float e = __expf(2.0f * x);
  return 1.0f - 2.0f / (e + 1.0f);
}
__device__ __forceinline__ unsigned short f2bf(float x) {   // RNE fp32->bf16
  unsigned u = __float_as_uint(x);
  u += 0x7fffu + ((u >> 16) & 1u);
  return (unsigned short)(u >> 16);
}
__device__ __forceinline__ float bf2f(unsigned short u) {
  return __uint_as_float(((unsigned)u) << 16);
}
__device__ __forceinline__ void gload_lds16(const unsigned short* g, unsigned short* l) {
  __builtin_amdgcn_global_load_lds(
      (const __attribute__((address_space(1))) unsigned int*)g,
      (__attribute__((address_space(3))) unsigned int*)l, 16, 0, 0);
}

// ---------------------------------------------------------------------------
// Kernel 1 (merged): blocks [0,128) = pos LSTM; blocks [128,2176) = xg GEMM.
// xg (bf16): stored with GATE-INTERLEAVED columns: col' = q*4 + g
// (q = hidden index 0..127, g = 0:i 1:f 2:g 3:o) so the batched LSTM's
// per-lane 4-gate read is one contiguous 8B load.
// ---------------------------------------------------------------------------
__global__ __launch_bounds__(256) void front_k(
    const int* __restrict__ words, const float* __restrict__ emb,
    const float* __restrict__ WiF, const float* __restrict__ WiB,
    const float* __restrict__ bF,  const float* __restrict__ bB,
    unsigned short* __restrict__ xg2,
    const int* __restrict__ pos,
    const float* __restrict__ pWiF, const float* __restrict__ pWhF, const float* __restrict__ pbF,
    const float* __restrict__ pWiB, const float* __restrict__ pWhB, const float* __restrict__ pbB,
    float* __restrict__ po) {
  const int tid = threadIdx.x;
  if (blockIdx.x < 128) {
    const int blk = blockIdx.x;
    const int b   = blk & 63;
    const int dir = blk >> 6;
    const float* __restrict__ Wi = dir ? pWiB : pWiF;   // [32][46]
    const float* __restrict__ Wh = dir ? pWhB : pWhF;   // [32][8]
    const float* __restrict__ bias = dir ? pbB : pbF;
    __shared__ float Wis[32 * P1_];
    for (int i = tid; i < 32 * P1_; i += 256) Wis[i] = Wi[i];
    __syncthreads();
    if (tid >= 64) return;
    const int lane = tid;
    float w[8] = {};
    float bi = 0.f;
    if (lane < 32) {
      #pragma unroll
      for (int j = 0; j < 8; ++j) w[j] = Wh[lane * 8 + j];
      bi = bias[lane];
    }
    float h[8] = {};
    float cc = 0.f;
    for (int s = 0; s < T_; ++s) {
      const int tt = dir ? (T_ - 1 - s) : s;
      const int p = pos[b * T_ + tt];
      float acc = 0.f;
      if (lane < 32) {
        acc = Wis[lane * P1_ + p] + bi;
        #pragma unroll
        for (int j = 0; j < 8; ++j) acc += w[j] * h[j];
      }
      const float act = (lane >= 16 && lane < 24) ? ftanh_(acc) : sigmoidf_(acc);
      const float a_f = __shfl_down(act, 8);
      const float a_g = __shfl_down(act, 16);
      const float a_o = __shfl_down(act, 24);
      float hnew = 0.f;
      if (lane < 8) {
        cc = a_f * cc + act * a_g;
        hnew = a_o * ftanh_(cc);
        po[(long)(b * T_ + tt) * 16 + dir * 8 + lane] = hnew;
      }
      #pragma unroll
      for (int j = 0; j < 8; ++j) h[j] = __shfl(hnew, j);
    }
    return;
  }
  // ---------------- xg GEMM (bf16 MFMA) ----------------
  __shared__ unsigned short Abuf[128 * 32];   // [row][32 k] bf16, slot^(row&3)
  __shared__ unsigned short Bbuf[64 * 32];
  const int xb = blockIdx.x - 128;            // 0..2047
  const int m0 = (xb & 127) * 128;
  const int n0 = (xb >> 7) * 64;
  const int w    = tid >> 6;
  const int lane = tid & 63;
  const int l15  = lane & 15;
  const int lg   = lane >> 4;
  const int mh   = w & 1;
  const int nh   = w >> 1;

  const int srow = tid >> 1;
  const int sfh  = tid & 1;
  const int aw   = words[m0 + srow];
  const float* __restrict__ arow = emb + (long)aw * EMB_;
  const int nrow = n0 + (srow & 63);
  const float* __restrict__ wrow = (nrow < G4_) ? (WiF + (long)nrow * EMB_)
                                                : (WiB + (long)(nrow - G4_) * EMB_);
  float biasv[2];
  #pragma unroll
  for (int nt = 0; nt < 2; ++nt) {
    const int n = n0 + nh * 32 + nt * 16 + l15;
    biasv[nt] = (n < G4_) ? bF[n] : bB[n - G4_];
  }

  f32x4 acc[4][2];
  #pragma unroll
  for (int mt = 0; mt < 4; ++mt)
    #pragma unroll
    for (int nt = 0; nt < 2; ++nt) acc[mt][nt] = (f32x4){0.f, 0.f, 0.f, 0.f};

  for (int k0 = 0; k0 < 320; k0 += 32) {
    float av[16], bv[16];
    #pragma unroll
    for (int j = 0; j < 4; ++j) {
      const int k = k0 + sfh * 16 + j * 4;
      float4 v = (k < EMB_) ? *(const float4*)(arow + k) : make_float4(0.f,0.f,0.f,0.f);
      av[j*4+0] = v.x; av[j*4+1] = v.y; av[j*4+2] = v.z; av[j*4+3] = v.w;
      if (tid < 128) {
        float4 u = (k < EMB_) ? *(const float4*)(wrow + k) : make_float4(0.f,0.f,0.f,0.f);
        bv[j*4+0] = u.x; bv[j*4+1] = u.y; bv[j*4+2] = u.z; bv[j*4+3] = u.w;
      }
    }
    __syncthreads();
    {
      union { unsigned short u[8]; short8 v; } p0, p1;
      #pragma unroll
      for (int e = 0; e < 8; ++e) { p0.u[e] = f2bf(av[e]); p1.u[e] = f2bf(av[8+e]); }
      const int sl0 = (2 * sfh + 0) ^ (srow & 3);
      const int sl1 = (2 * sfh + 1) ^ (srow & 3);
      *(short8*)&Abuf[srow * 32 + sl0 * 8] = p0.v;
      *(short8*)&Abuf[srow * 32 + sl1 * 8] = p1.v;
      if (tid < 128) {
        union { unsigned short u[8]; short8 v; } q0, q1;
        #pragma unroll
        for (int e = 0; e < 8; ++e) { q0.u[e] = f2bf(bv[e]); q1.u[e] = f2bf(bv[8+e]); }
        *(short8*)&Bbuf[srow * 32 + sl0 * 8] = q0.v;
        *(short8*)&Bbuf[srow * 32 + sl1 * 8] = q1.v;
      }
    }
    __syncthreads();
    short8 bfr[2];
    #pragma unroll
    for (int nt = 0; nt < 2; ++nt) {
      const int r = nh * 32 + nt * 16 + l15;
      const int sl = lg ^ (r & 3);
      bfr[nt] = *(const short8*)&Bbuf[r * 32 + sl * 8];
    }
    #pragma unroll
    for (int mt = 0; mt < 4; ++mt) {
      const int r = mh * 64 + mt * 16 + l15;
      const int sl = lg ^ (r & 3);
      const short8 af = *(const short8*)&Abuf[r * 32 + sl * 8];
      #pragma unroll
      for (int nt = 0; nt < 2; ++nt)
        acc[mt][nt] = __builtin_amdgcn_mfma_f32_16x16x32_bf16(af, bfr[nt], acc[mt][nt], 0, 0, 0);
    }
  }
  #pragma unroll
  for (int nt = 0; nt < 2; ++nt) {
    const int n = n0 + nh * 32 + nt * 16 + l15;
    const int dir = n >> 9, c = n & 511;
    const int gg = c >> 7, rr = c & 127;
    const int cp = rr * 4 + gg;                      // gate-interleaved column
    #pragma unroll
    for (int mt = 0; mt < 4; ++mt) {
      #pragma unroll
      for (int r = 0; r < 4; ++r) {
        const int m = m0 + mh * 64 + mt * 16 + lg * 4 + r;
        const int bb_ = m >> 8, tt = m & 255;
        xg2[(long)(((dir * 256 + tt) * 64) + bb_) * 512 + cp] =
            f2bf(acc[mt][nt][r] + biasv[nt]);
      }
    }
  }
}

// ---------------------------------------------------------------------------
// Kernel 2: BATCHED word LSTM. 8 blocks = (bgroup 0..3, dir), 512 thr (8 waves).
// Per step: G[16 seq][512] = H[16][128] @ Wh_perm^T as 128 MFMA, all M useful.
// Wh rows gate-interleaved (row = q*4+g)  =>  each lane's 4 acc regs of tile
// nt are gates i,f,g,o of q = nt*4+lg for batch l15 — c/h update is IN-LANE.
// One barrier/step. xg register-prefetched 2 steps ahead. wo flushed per step.
// ---------------------------------------------------------------------------
__global__ __launch_bounds__(512) void word_lstm_batch(
    const unsigned short* __restrict__ xgb,   // [(dir*256+t)*64+b]*512 + q*4+g
    const float* __restrict__ WhF, const float* __restrict__ WhB,
    unsigned short* __restrict__ wo) {        // [(b*256+t)*256 + dir*128+q] bf16
  const int dir = blockIdx.x & 1;
  const int bg  = blockIdx.x >> 1;            // 0..3
  const int tid = threadIdx.x;
  const int w   = tid >> 6;                   // wave 0..7: tiles w*4..w*4+3
  const int lane = tid & 63;
  const int l15 = lane & 15;                  // A-row / batch col
  const int lg  = lane >> 4;                  // 0..3
  const float* __restrict__ Wh = dir ? WhB : WhF;
  const int b = bg * 16 + l15;                // this lane's batch (as B-col)

  __shared__ __align__(16) unsigned short h_lds[2][16][136];  // 272B rows (16B align)

  // A-frags: tile nt = w*4+j, lane m=l15 -> interleaved row R = nt*16+l15
  //   -> q = nt*4 + (l15>>2), g = l15&3 ; orig Wh row = g*128+q ; k = kf*32+lg*8+e
  short8 afr[4][4];
  {
    const int g = l15 & 3;
    #pragma unroll
    for (int j = 0; j < 4; ++j) {
      const int q = (w * 4 + j) * 4 + (l15 >> 2);
      const float* p0 = Wh + (long)(g * 128 + q) * 128;
      #pragma unroll
      for (int kf = 0; kf < 4; ++kf) {
        const float4 f0 = *(const float4*)(p0 + kf * 32 + lg * 8);
        const float4 f1 = *(const float4*)(p0 + kf * 32 + lg * 8 + 4);
        union { unsigned short u[8]; short8 v; } t;
        t.u[0]=f2bf(f0.x); t.u[1]=f2bf(f0.y); t.u[2]=f2bf(f0.z); t.u[3]=f2bf(f0.w);
        t.u[4]=f2bf(f1.x); t.u[5]=f2bf(f1.y); t.u[6]=f2bf(f1.z); t.u[7]=f2bf(f1.w);
        afr[j][kf] = t.v;
      }
    }
  }

  // zero both h buffers (2*16*136 ushorts = 2176 dwords)
  for (int i = tid; i < 2176; i += 512) ((unsigned*)h_lds)[i] = 0u;

  // xg register prefetch: per lane 4x ushort4 (gates of q=(w*4+j)*4+lg)
  ushort4 xq0[4], xq1[4], xq2[4];
  const unsigned short* xbase = xgb + (long)(dir * 256) * 32768 + (long)b * 512
                                + w * 64 + lg * 4;
  {
    const int t0 = dir ? 255 : 0;
    const int t1 = dir ? 254 : 1;
    #pragma unroll
    for (int j = 0; j < 4; ++j) {
      xq0[j] = *(const ushort4*)(xbase + (long)t0 * 32768 + j * 16);
      xq1[j] = *(const ushort4*)(xbase + (long)t1 * 32768 + j * 16);
    }
  }
  float cst[4] = {0.f, 0.f, 0.f, 0.f};
  __syncthreads();

  for (int s = 0; s < T_; ++s) {
    const int cb = s & 1;
    // prefetch step s+2
    if (s + 2 < T_) {
      const int tn = dir ? (253 - s) : (s + 2);
      #pragma unroll
      for (int j = 0; j < 4; ++j)
        xq2[j] = *(const ushort4*)(xbase + (long)tn * 32768 + j * 16);
    }
    // B-frags: h^T — lane n=l15=batch reads its h row (b128, 2-way-free banks)
    short8 bfr[4];
    #pragma unroll
    for (int kf = 0; kf < 4; ++kf)
      bfr[kf] = *(const short8*)&h_lds[cb][l15][kf * 32 + lg * 8];
    // 16 MFMA
    f32x4 acc[4];
    #pragma unroll
    for (int j = 0; j < 4; ++j) {
      f32x4 a = {0.f, 0.f, 0.f, 0.f};
      #pragma unroll
      for (int kf = 0; kf < 4; ++kf)
        a = __builtin_amdgcn_mfma_f32_16x16x32_bf16(afr[j][kf], bfr[kf], a, 0, 0, 0);
      acc[j] = a;
    }
    // in-lane gates: acc[j][r] = gate r of q=(w*4+j)*4+lg for batch l15
    #pragma unroll
    for (int j = 0; j < 4; ++j) {
      const float i_s = sigmoidf_(acc[j][0] + bf2f(xq0[j].x));
      const float f_s = sigmoidf_(acc[j][1] + bf2f(xq0[j].y));
      const float g_t = ftanh_  (acc[j][2] + bf2f(xq0[j].z));
      const float o_s = sigmoidf_(acc[j][3] + bf2f(xq0[j].w));
      cst[j] = f_s * cst[j] + i_s * g_t;
      const float hh = o_s * ftanh_(cst[j]);
      h_lds[cb ^ 1][l15][w * 16 + j * 4 + lg] = f2bf(hh);
    }
    // flush previous step's h (h_lds[cb]) to wo, coalesced 8B/thread
    if (s > 0) {
      const int tp  = dir ? (256 - s) : (s - 1);
      const int seq = tid >> 5;               // 0..15
      const int prt = tid & 31;               // 0..31
      const ushort4 v = *(const ushort4*)&h_lds[cb][seq][prt * 4];
      *(ushort4*)&wo[((long)((bg * 16 + seq) * 256 + tp)) * 256 + dir * 128 + prt * 4] = v;
    }
    // rotate xg prefetch regs
    #pragma unroll
    for (int j = 0; j < 4; ++j) { xq0[j] = xq1[j]; xq1[j] = xq2[j]; }
    asm volatile("s_waitcnt lgkmcnt(0)" ::: "memory");
    __builtin_amdgcn_s_barrier();
  }
  // final flush: h of step 255 is in h_lds[0]
  {
    const int tp  = dir ? 0 : 255;
    const int seq = tid >> 5;
    const int prt = tid & 31;
    const ushort4 v = *(const ushort4*)&h_lds[0][seq][prt * 4];
    *(ushort4*)&wo[((long)((bg * 16 + seq) * 256 + tp)) * 256 + dir * 128 + prt * 4] = v;
  }
}

// ---------------------------------------------------------------------------
// Kernel 3 (fused): wh = relu(wo @ whW^T + whb) ; ph = relu(po@phW^T+phb);
// feats = relu([wh,ph] @ tagW^T + tagb).  bf16 MFMA, M-tile 128, N=128, K=256.
// ---------------------------------------------------------------------------
__global__ __launch_bounds__(256) void wh_feats_k(
    const unsigned short* __restrict__ wo,   // [NPOS][256] bf16
    const float* __restrict__ whW, const float* __restrict__ whb,
    const float* __restrict__ po,  const float* __restrict__ phW,
    const float* __restrict__ phb, const float* __restrict__ tagW,
    const float* __restrict__ tagb, float* __restrict__ feats) {
  __shared__ unsigned short Ast[2][128 * 32];    // 8KB x2, 16B-slot ^ (row&3)
  __shared__ unsigned short whs[128 * 128];      // 32KB wh tile bf16, swizzled
  __shared__ float tagWs[6 * 136], tagbs[6], phWs[128], phbs[8], whbs[128];
  const int m0  = blockIdx.x * 128;
  const int tid = threadIdx.x;
  const int w   = tid >> 6;
  const int lane = tid & 63;
  const int l15 = lane & 15, lg = lane >> 4;

  for (int i = tid; i < 816; i += 256) tagWs[i] = tagW[i];
  if (tid < 6)   tagbs[tid] = tagb[tid];
  if (tid < 128) phWs[tid]  = phW[tid];
  if (tid < 8)   phbs[tid]  = phb[tid];
  if (tid < 128) whbs[tid]  = whb[tid];

  short8 bfr[2][8];
  #pragma unroll
  for (int nt = 0; nt < 2; ++nt) {
    const int n = w * 32 + nt * 16 + l15;
    #pragma unroll
    for (int kf = 0; kf < 8; ++kf) {
      const float* p = whW + (long)n * 256 + kf * 32 + lg * 8;
      const float4 f0 = *(const float4*)p;
      const float4 f1 = *(const float4*)(p + 4);
      union { unsigned short u[8]; short8 v; } t;
      t.u[0]=f2bf(f0.x); t.u[1]=f2bf(f0.y); t.u[2]=f2bf(f0.z); t.u[3]=f2bf(f0.w);
      t.u[4]=f2bf(f1.x); t.u[5]=f2bf(f1.y); t.u[6]=f2bf(f1.z); t.u[7]=f2bf(f1.w);
      bfr[nt][kf] = t.v;
    }
  }

  auto stageA = [&](int kc, int pb) {
    #pragma unroll
    for (int c = 0; c < 2; ++c) {
      const int row  = c * 64 + (tid >> 2);
      const int slot = tid & 3;
      const unsigned short* gp =
          wo + (long)(m0 + row) * 256 + kc * 32 + ((slot ^ (row & 3)) << 3);
      unsigned short* lb = &Ast[pb][0] + c * 2048 + ((tid & ~63) << 3);
      gload_lds16(gp, lb);
    }
  };

  f32x4 acc[8][2];
  #pragma unroll
  for (int mt = 0; mt < 8; ++mt)
    #pragma unroll
    for (int nt = 0; nt < 2; ++nt) acc[mt][nt] = (f32x4){0.f,0.f,0.f,0.f};

  stageA(0, 0);
  asm volatile("s_waitcnt vmcnt(0)" ::: "memory");
  __syncthreads();
  for (int kc = 0; kc < 8; ++kc) {
    if (kc < 7) stageA(kc + 1, (kc + 1) & 1);
    const unsigned short* ab = &Ast[kc & 1][0];
    #pragma unroll
    for (int mt = 0; mt < 8; ++mt) {
      const int row = mt * 16 + l15;
      const short8 af = *(const short8*)(ab + row * 32 + ((lg ^ (row & 3)) << 3));
      #pragma unroll
      for (int nt = 0; nt < 2; ++nt)
        acc[mt][nt] = __builtin_amdgcn_mfma_f32_16x16x32_bf16(af, bfr[nt][kc], acc[mt][nt], 0, 0, 0);
    }
    if (kc < 7) {
      asm volatile("s_waitcnt vmcnt(0)" ::: "memory");
      __syncthreads();
    }
  }
  #pragma unroll
  for (int nt = 0; nt < 2; ++nt) {
    const int col = w * 32 + nt * 16 + l15;
    const float bv = whbs[col];
    #pragma unroll
    for (int mt = 0; mt < 8; ++mt) {
      #pragma unroll
      for (int r = 0; r < 4; ++r) {
        const int row = mt * 16 + lg * 4 + r;
        const int cs = col ^ ((row & 7) << 3);
        whs[row * 128 + cs] = f2bf(fmaxf(acc[mt][nt][r] + bv, 0.f));
      }
    }
  }
  __syncthreads();
  {
    const int row = tid >> 1, kh = tid & 1;
    float f[6] = {0.f, 0.f, 0.f, 0.f, 0.f, 0.f};
    #pragma unroll
    for (int ks = 0; ks < 8; ++ks) {
      const int k0 = kh * 64 + ks * 8;
      const int slot = (k0 >> 3) ^ (row & 7);
      const short8 v8 = *(const short8*)&whs[row * 128 + slot * 8];
      #pragma unroll
      for (int e = 0; e < 8; ++e) {
        const float wv = bf2f(((unsigned short)v8[e]));
        #pragma unroll
        for (int o = 0; o < 6; ++o) f[o] += wv * tagWs[o * 136 + k0 + e];
      }
    }
    if (kh == 1) {
      const float* pr = po + (long)(m0 + row) * 16;
      float pv[16];
      #pragma unroll
      for (int i = 0; i < 16; i += 4) {
        const float4 v = *(const float4*)(pr + i);
        pv[i] = v.x; pv[i+1] = v.y; pv[i+2] = v.z; pv[i+3] = v.w;
      }
      #pragma unroll
      for (int o8 = 0; o8 < 8; ++o8) {
        float a = phbs[o8];
        #pragma unroll
        for (int k = 0; k < 16; ++k) a += pv[k] * phWs[o8 * 16 + k];
        a = fmaxf(a, 0.f);
        #pragma unroll
        for (int o = 0; o < 6; ++o) f[o] += a * tagWs[o * 136 + 128 + o8];
      }
    }
    #pragma unroll
    for (int o = 0; o < 6; ++o) f[o] += __shfl_xor(f[o], 1);
    if (kh == 0) {
      #pragma unroll
      for (int o = 0; o < 6; ++o)
        feats[(long)(m0 + row) * 6 + o] = fmaxf(f[o] + tagbs[o], 0.f);
    }
  }
}

// ---------------------------------------------------------------------------
// Kernel 4: CRF NLL. One block, 512 threads: 8 lanes per batch element.
// ---------------------------------------------------------------------------
__global__ __launch_bounds__(512) void crf_k(
    const int* __restrict__ words, const int* __restrict__ labels,
    const float* __restrict__ feats, const float* __restrict__ trans,
    float* __restrict__ out) {
  __shared__ float tn_s[36];
  __shared__ float tE_s[6];
  __shared__ float res_s[64];
  const int tid = threadIdx.x;
  if (tid < 36) {
    const int nx = tid / 6, pv = tid % 6;
    float mx = -1e30f;
    for (int q = 0; q < 6; ++q) mx = fmaxf(mx, trans[q * 6 + pv]);
    float s = 0.f;
    for (int q = 0; q < 6; ++q) s += __expf(trans[q * 6 + pv] - mx);
    tn_s[tid] = (pv == 4) ? -100.f : (__expf(trans[nx * 6 + pv] - mx) / s);
  }
  if (tid < 6) tE_s[tid] = trans[4 * 6 + tid];
  __syncthreads();

  const int lane = tid & 63;
  const int wv   = tid >> 6;
  const int sub  = lane & 7;
  const int b    = wv * 8 + (lane >> 3);

  int cnt = 0;
  for (int t = sub; t < T_; t += 8) cnt += (words[b * T_ + t] != 0) ? 1 : 0;
  cnt += __shfl_xor(cnt, 1); cnt += __shfl_xor(cnt, 2); cnt += __shfl_xor(cnt, 4);
  const int len = cnt;

  float tnr[6];
  #pragma unroll
  for (int p = 0; p < 6; ++p) tnr[p] = (sub < 6) ? tn_s[sub * 6 + p] : -100.f;
  float alpha = (sub == 3) ? 0.f : -100.f;
  for (int t = 0; t < T_; ++t) {
    float ap[6];
    #pragma unroll
    for (int p = 0; p < 6; ++p) ap[p] = __shfl(alpha, p, 8) + tnr[p];
    const float feat = (sub < 6) ? feats[(long)(b * T_ + t) * 6 + sub] : 0.f;
    float m = ap[0];
    #pragma unroll
    for (int p = 1; p < 6; ++p) m = fmaxf(m, ap[p]);
    float s = 0.f;
    #pragma unroll
    for (int p = 0; p < 6; ++p) s += __expf(ap[p] - m);
    const float anew = m + __logf(s) + feat;
    alpha = (t < len) ? anew : alpha;
  }
  float v = (sub < 6) ? (alpha + tE_s[sub]) : -1e30f;
  float m2 = v;
  m2 = fmaxf(m2, __shfl_xor(m2, 1));
  m2 = fmaxf(m2, __shfl_xor(m2, 2));
  m2 = fmaxf(m2, __shfl_xor(m2, 4));
  float e = (sub < 6) ? __expf(v - m2) : 0.f;
  e += __shfl_xor(e, 1); e += __shfl_xor(e, 2); e += __shfl_xor(e, 4);
  const float fwd = m2 + __logf(e);

  int fp = T_;
  for (int t = sub; t < T_; t += 8)
    if (labels[b * T_ + t] == 5) fp = min(fp, t);
  fp = min(fp, __shfl_xor(fp, 1));
  fp = min(fp, __shfl_xor(fp, 2));
  fp = min(fp, __shfl_xor(fp, 4));
  float gs = 0.f;
  for (int t = sub; t < T_; t += 8) {
    if (t < fp) {
      const int lab = labels[b * T_ + t];
      const int prv = (t == 0) ? 3 : labels[b * T_ + t - 1];
      gs += feats[(long)(b * T_ + t) * 6 + lab] + tn_s[lab * 6 + prv];
    }
  }
  gs += __shfl_xor(gs, 1); gs += __shfl_xor(gs, 2); gs += __shfl_xor(gs, 4);
  const float gold = gs + trans[4 * 6 + labels[b * T_ + T_ - 1]];
  if (sub == 0) res_s[b] = fwd - gold;
  __syncthreads();
  if (tid == 0) {
    float r = 0.f;
    for (int i = 0; i < 64; ++i) r += res_s[i];
    out[0] = r * (1.0f / 64.0f);
  }
}

// ---------------------------------------------------------------------------
extern "C" void kernel_launch(void* const* d_in, const int* in_sizes, int n_in,
                              void* d_out, int out_size, void* d_ws, size_t ws_size,
                              hipStream_t stream) {
  (void)in_sizes; (void)n_in; (void)out_size; (void)ws_size;
  const int*   words = (const int*)d_in[0];
  const int*   postg = (const int*)d_in[1];
  const int*   labels= (const int*)d_in[2];
  const float* emb_w = (const float*)d_in[3];
  const float* wlfWi = (const float*)d_in[5];
  const float* wlfWh = (const float*)d_in[6];
  const float* wlfb  = (const float*)d_in[7];
  const float* wlbWi = (const float*)d_in[8];
  const float* wlbWh = (const float*)d_in[9];
  const float* wlbb  = (const float*)d_in[10];
  const float* plfWi = (const float*)d_in[11];
  const float* plfWh = (const float*)d_in[12];
  const float* plfb  = (const float*)d_in[13];
  const float* plbWi = (const float*)d_in[14];
  const float* plbWh = (const float*)d_in[15];
  const float* plbb  = (const float*)d_in[16];
  const float* whW   = (const float*)d_in[17];
  const float* whb   = (const float*)d_in[18];
  const float* phW   = (const float*)d_in[19];
  const float* phb   = (const float*)d_in[20];
  const float* tagW  = (const float*)d_in[21];
  const float* tagb  = (const float*)d_in[22];
  const float* trans = (const float*)d_in[23];

  float* ws = (float*)d_ws;
  unsigned short* xg = (unsigned short*)ws;                 // bf16 [2][256][64][512]
  unsigned short* wo = (unsigned short*)(ws + (size_t)NPOS * 1024); // bf16 [NPOS][256]
  float* po = ws + (size_t)NPOS * 1024 + (size_t)NPOS * 256; // fp32 [NPOS][16]
  float* fe = po + (size_t)NPOS * 16;                        // fp32 [NPOS][6]

  hipLaunchKernelGGL(front_k, dim3(128 + 2048), dim3(256), 0, stream,
                     words, emb_w, wlfWi, wlbWi, wlfb, wlbb, xg,
                     postg, plfWi, plfWh, plfb, plbWi, plbWh, plbb, po);
  hipLaunchKernelGGL(word_lstm_batch, dim3(8), dim3(512), 0, stream,
                     xg, wlfWh, wlbWh, wo);
  hipLaunchKernelGGL(wh_feats_k, dim3(NPOS / 128), dim3(256), 0, stream,
                     wo, whW, whb, po, phW, phb, tagW, tagb, fe);
  hipLaunchKernelGGL(crf_k, dim3(1), dim3(512), 0, stream,
                     words, labels, fe, trans, (float*)d_out);
}

// Round 10
// 480.674 us; speedup vs baseline: 1.3278x; 1.3278x over previous
//
#include <hip/hip_runtime.h>
#include <hip/hip_bf16.h>
#include <math.h>

#define B_    64
#define T_    256
#define EMB_  300
#define HW_   128
#define G4_   512     // 4*HW
#define P1_   46
#define NPOS  (B_*T_) // 16384

typedef short  short8 __attribute__((ext_vector_type(8)));
typedef float  f32x4  __attribute__((ext_vector_type(4)));

__device__ __forceinline__ float sigmoidf_(float x) {
  return 1.0f / (1.0f + __expf(-x));
}
__device__ __forceinline__ float ftanh_(float x) {
  float e = __expf(2.0f * x);
  return 1.0f - 2.0f / (e + 1.0f);
}
__device__ __forceinline__ unsigned short f2bf(float x) {   // RNE fp32->bf16
  unsigned u = __float_as_uint(x);
  u += 0x7fffu + ((u >> 16) & 1u);
  return (unsigned short)(u >> 16);
}
__device__ __forceinline__ float bf2f(unsigned short u) {
  return __uint_as_float(((unsigned)u) << 16);
}
template<int CTRL>
__device__ __forceinline__ float qb(float v) {   // quad_perm broadcast (DPP, VALU)
  return __int_as_float(__builtin_amdgcn_mov_dpp(__float_as_int(v), CTRL, 0xf, 0xf, true));
}
__device__ __forceinline__ void gload_lds16(const unsigned short* g, unsigned short* l) {
  __builtin_amdgcn_global_load_lds(
      (const __attribute__((address_space(1))) unsigned int*)g,
      (__attribute__((address_space(3))) unsigned int*)l, 16, 0, 0);
}

// ---------------------------------------------------------------------------
// Kernel 1 (merged): blocks [0,128) = pos LSTM; blocks [128,2176) = xg GEMM.
// xg (bf16): gate-block g's columns rotated by g*8 (LSTM xbuf bank spread).
// ---------------------------------------------------------------------------
__global__ __launch_bounds__(256) void front_k(
    const int* __restrict__ words, const float* __restrict__ emb,
    const float* __restrict__ WiF, const float* __restrict__ WiB,
    const float* __restrict__ bF,  const float* __restrict__ bB,
    unsigned short* __restrict__ xg2,
    const int* __restrict__ pos,
    const float* __restrict__ pWiF, const float* __restrict__ pWhF, const float* __restrict__ pbF,
    const float* __restrict__ pWiB, const float* __restrict__ pWhB, const float* __restrict__ pbB,
    float* __restrict__ po) {
  const int tid = threadIdx.x;
  if (blockIdx.x < 128) {
    const int blk = blockIdx.x;
    const int b   = blk & 63;
    const int dir = blk >> 6;
    const float* __restrict__ Wi = dir ? pWiB : pWiF;   // [32][46]
    const float* __restrict__ Wh = dir ? pWhB : pWhF;   // [32][8]
    const float* __restrict__ bias = dir ? pbB : pbF;
    __shared__ float Wis[32 * P1_];
    for (int i = tid; i < 32 * P1_; i += 256) Wis[i] = Wi[i];
    __syncthreads();
    if (tid >= 64) return;
    const int lane = tid;
    float w[8] = {};
    float bi = 0.f;
    if (lane < 32) {
      #pragma unroll
      for (int j = 0; j < 8; ++j) w[j] = Wh[lane * 8 + j];
      bi = bias[lane];
    }
    float h[8] = {};
    float cc = 0.f;
    for (int s = 0; s < T_; ++s) {
      const int tt = dir ? (T_ - 1 - s) : s;
      const int p = pos[b * T_ + tt];
      float acc = 0.f;
      if (lane < 32) {
        acc = Wis[lane * P1_ + p] + bi;
        #pragma unroll
        for (int j = 0; j < 8; ++j) acc += w[j] * h[j];
      }
      const float act = (lane >= 16 && lane < 24) ? ftanh_(acc) : sigmoidf_(acc);
      const float a_f = __shfl_down(act, 8);
      const float a_g = __shfl_down(act, 16);
      const float a_o = __shfl_down(act, 24);
      float hnew = 0.f;
      if (lane < 8) {
        cc = a_f * cc + act * a_g;
        hnew = a_o * ftanh_(cc);
        po[(long)(b * T_ + tt) * 16 + dir * 8 + lane] = hnew;
      }
      #pragma unroll
      for (int j = 0; j < 8; ++j) h[j] = __shfl(hnew, j);
    }
    return;
  }
  // ---------------- xg GEMM (bf16 MFMA) ----------------
  __shared__ unsigned short Abuf[128 * 32];   // [row][32 k] bf16, slot^(row&3)
  __shared__ unsigned short Bbuf[64 * 32];
  const int xb = blockIdx.x - 128;            // 0..2047
  const int m0 = (xb & 127) * 128;
  const int n0 = (xb >> 7) * 64;
  const int w    = tid >> 6;
  const int lane = tid & 63;
  const int l15  = lane & 15;
  const int lg   = lane >> 4;
  const int mh   = w & 1;
  const int nh   = w >> 1;

  const int srow = tid >> 1;
  const int sfh  = tid & 1;
  const int aw   = words[m0 + srow];
  const float* __restrict__ arow = emb + (long)aw * EMB_;
  const int nrow = n0 + (srow & 63);
  const float* __restrict__ wrow = (nrow < G4_) ? (WiF + (long)nrow * EMB_)
                                                : (WiB + (long)(nrow - G4_) * EMB_);
  float biasv[2];
  #pragma unroll
  for (int nt = 0; nt < 2; ++nt) {
    const int n = n0 + nh * 32 + nt * 16 + l15;
    biasv[nt] = (n < G4_) ? bF[n] : bB[n - G4_];
  }

  f32x4 acc[4][2];
  #pragma unroll
  for (int mt = 0; mt < 4; ++mt)
    #pragma unroll
    for (int nt = 0; nt < 2; ++nt) acc[mt][nt] = (f32x4){0.f, 0.f, 0.f, 0.f};

  for (int k0 = 0; k0 < 320; k0 += 32) {
    float av[16], bv[16];
    #pragma unroll
    for (int j = 0; j < 4; ++j) {
      const int k = k0 + sfh * 16 + j * 4;
      float4 v = (k < EMB_) ? *(const float4*)(arow + k) : make_float4(0.f,0.f,0.f,0.f);
      av[j*4+0] = v.x; av[j*4+1] = v.y; av[j*4+2] = v.z; av[j*4+3] = v.w;
      if (tid < 128) {
        float4 u = (k < EMB_) ? *(const float4*)(wrow + k) : make_float4(0.f,0.f,0.f,0.f);
        bv[j*4+0] = u.x; bv[j*4+1] = u.y; bv[j*4+2] = u.z; bv[j*4+3] = u.w;
      }
    }
    __syncthreads();
    {
      union { unsigned short u[8]; short8 v; } p0, p1;
      #pragma unroll
      for (int e = 0; e < 8; ++e) { p0.u[e] = f2bf(av[e]); p1.u[e] = f2bf(av[8+e]); }
      const int sl0 = (2 * sfh + 0) ^ (srow & 3);
      const int sl1 = (2 * sfh + 1) ^ (srow & 3);
      *(short8*)&Abuf[srow * 32 + sl0 * 8] = p0.v;
      *(short8*)&Abuf[srow * 32 + sl1 * 8] = p1.v;
      if (tid < 128) {
        union { unsigned short u[8]; short8 v; } q0, q1;
        #pragma unroll
        for (int e = 0; e < 8; ++e) { q0.u[e] = f2bf(bv[e]); q1.u[e] = f2bf(bv[8+e]); }
        *(short8*)&Bbuf[srow * 32 + sl0 * 8] = q0.v;
        *(short8*)&Bbuf[srow * 32 + sl1 * 8] = q1.v;
      }
    }
    __syncthreads();
    short8 bfr[2];
    #pragma unroll
    for (int nt = 0; nt < 2; ++nt) {
      const int r = nh * 32 + nt * 16 + l15;
      const int sl = lg ^ (r & 3);
      bfr[nt] = *(const short8*)&Bbuf[r * 32 + sl * 8];
    }
    #pragma unroll
    for (int mt = 0; mt < 4; ++mt) {
      const int r = mh * 64 + mt * 16 + l15;
      const int sl = lg ^ (r & 3);
      const short8 af = *(const short8*)&Abuf[r * 32 + sl * 8];
      #pragma unroll
      for (int nt = 0; nt < 2; ++nt)
        acc[mt][nt] = __builtin_amdgcn_mfma_f32_16x16x32_bf16(af, bfr[nt], acc[mt][nt], 0, 0, 0);
    }
  }
  #pragma unroll
  for (int nt = 0; nt < 2; ++nt) {
    const int n = n0 + nh * 32 + nt * 16 + l15;
    const int dir = n >> 9, c = n & 511;
    const int gg = c >> 7, rr = c & 127;
    const int cp = gg * 128 + ((rr + gg * 8) & 127);
    #pragma unroll
    for (int mt = 0; mt < 4; ++mt) {
      #pragma unroll
      for (int r = 0; r < 4; ++r) {
        const int m = m0 + mh * 64 + mt * 16 + lg * 4 + r;
        const int bb_ = m >> 8, tt = m & 255;
        xg2[(long)(((dir * 256 + tt) * 64) + bb_) * 512 + cp] =
            f2bf(acc[mt][nt][r] + biasv[nt]);
      }
    }
  }
}

// ---------------------------------------------------------------------------
// Kernel 2: word LSTM (MFMA + DPP gates), R8 configuration. wo emitted bf16.
// ---------------------------------------------------------------------------
__global__ __launch_bounds__(512) void word_lstm_mfma3(
    const unsigned short* __restrict__ xgb, const float* __restrict__ WhF,
    const float* __restrict__ WhB, unsigned short* __restrict__ wo) {
  const int b    = blockIdx.x >> 1;
  const int dir  = blockIdx.x & 1;
  const int tid  = threadIdx.x;
  const int w    = tid >> 6;
  const int lane = tid & 63;
  const int l15  = lane & 15;
  const int lg   = lane >> 4;
  const int g    = lane & 3;
  const int qloc = l15 >> 2;
  const float* __restrict__ Wh = dir ? WhB : WhF;

  __shared__ unsigned short xbuf[2][16 * 512];            // 32 KB
  __shared__ unsigned short wo_stage[2][16][128];         // 8 KB bf16
  __shared__ __align__(16) unsigned short h2[2][128];

  short8 bfr[4][4];
  #pragma unroll
  for (int nt = 0; nt < 4; ++nt) {
    const int q = w * 16 + nt * 4 + qloc;
    const int r = g * 128 + q;
    #pragma unroll
    for (int kf = 0; kf < 4; ++kf) {
      const float* p = Wh + (long)r * 128 + kf * 32 + lg * 8;
      const float4 f0 = *(const float4*)p;
      const float4 f1 = *(const float4*)(p + 4);
      union { unsigned short u[8]; short8 v; } t;
      t.u[0]=f2bf(f0.x); t.u[1]=f2bf(f0.y); t.u[2]=f2bf(f0.z); t.u[3]=f2bf(f0.w);
      t.u[4]=f2bf(f1.x); t.u[5]=f2bf(f1.y); t.u[6]=f2bf(f1.z); t.u[7]=f2bf(f1.w);
      bfr[nt][kf] = t.v;
    }
  }

  if (tid < 128) { h2[0][tid] = 0; h2[1][tid] = 0; }

  auto stage = [&](int cc, int bb) {
    #pragma unroll
    for (int k = 0; k < 2; ++k) {
      const int j = k * 8 + w;
      const int s_abs = cc * 16 + j;
      const int t = dir ? 255 - s_abs : s_abs;
      const unsigned short* gp =
          xgb + (((long)(dir * 256 + t) * 64 + b) << 9) + lane * 8;
      gload_lds16(gp, &xbuf[bb][j * 512]);
    }
  };

  float cst[4] = {0.f, 0.f, 0.f, 0.f};
  const float kmul = (g == 2) ? 2.f : 1.f;
  const float amul = (g == 2) ? 2.f : 1.f;
  const float aadd = (g == 2) ? -1.f : 0.f;
  int xcol[4];
  #pragma unroll
  for (int nt = 0; nt < 4; ++nt)
    xcol[nt] = g * 128 + ((w * 16 + qloc + nt * 4 + g * 8) & 127);

  stage(0, 0);
  asm volatile("s_waitcnt vmcnt(0)" ::: "memory");
  asm volatile("s_waitcnt lgkmcnt(0)" ::: "memory");
  __builtin_amdgcn_s_barrier();
  stage(1, 1);

  for (int s = 0; s < T_; ++s) {
    const int cc = s >> 4, j = s & 15, cb = cc & 1;
    const unsigned short* hb = h2[s & 1];
    short8 af[4];
    #pragma unroll
    for (int kf = 0; kf < 4; ++kf)
      af[kf] = *(const short8*)(hb + kf * 32 + lg * 8);
    float xqv[4];
    #pragma unroll
    for (int nt = 0; nt < 4; ++nt) {
      const unsigned u = xbuf[cb][j * 512 + xcol[nt]];
      xqv[nt] = __uint_as_float(u << 16);
    }
    f32x4 acc[4];
    #pragma unroll
    for (int nt = 0; nt < 4; ++nt) {
      f32x4 a = {0.f, 0.f, 0.f, 0.f};
      #pragma unroll
      for (int kf = 0; kf < 4; ++kf)
        a = __builtin_amdgcn_mfma_f32_16x16x32_bf16(af[kf], bfr[nt][kf], a, 0, 0, 0);
      acc[nt] = a;
    }
    #pragma unroll
    for (int nt = 0; nt < 4; ++nt) {
      const float x  = acc[nt][0] + xqv[nt];
      const float sg = 1.0f / (1.0f + __expf(-x * kmul));
      const float act = sg * amul + aadd;
      const float vi = qb<0x00>(act);
      const float vf = qb<0x55>(act);
      const float vg = qb<0xAA>(act);
      const float vo = qb<0xFF>(act);
      cst[nt] = vf * cst[nt] + vi * vg;
      const float e2 = __expf(2.0f * cst[nt]);
      const float th = 1.0f - 2.0f / (e2 + 1.0f);
      const float hh = vo * th;
      const unsigned short hb16 = f2bf(hh);
      if (lane < 16 && g == 0) {
        const int q = w * 16 + nt * 4 + qloc;
        h2[(s + 1) & 1][q] = hb16;
        wo_stage[cb][j][q] = hb16;
      }
    }
    if (j == 15 && s < 255) {
      asm volatile("s_waitcnt vmcnt(0)" ::: "memory");
      asm volatile("s_waitcnt lgkmcnt(0)" ::: "memory");
      __builtin_amdgcn_s_barrier();
      {
        const int jf = tid >> 5, qc = (tid & 31) << 2;
        const int s_f = cc * 16 + jf;
        const int tf = dir ? 255 - s_f : s_f;
        const ushort4 v = *(const ushort4*)&wo_stage[cb][jf][qc];
        *(ushort4*)&wo[((long)(b * 256 + tf)) * 256 + dir * 128 + qc] = v;
      }
      if (cc + 2 <= 15) stage(cc + 2, cb);
    } else if (s < 255) {
      asm volatile("s_waitcnt lgkmcnt(0)" ::: "memory");
      __builtin_amdgcn_s_barrier();
    }
  }
  asm volatile("s_waitcnt lgkmcnt(0)" ::: "memory");
  __builtin_amdgcn_s_barrier();
  {
    const int jf = tid >> 5, qc = (tid & 31) << 2;
    const int s_f = 15 * 16 + jf;
    const int tf = dir ? 255 - s_f : s_f;
    const ushort4 v = *(const ushort4*)&wo_stage[1][jf][qc];
    *(ushort4*)&wo[((long)(b * 256 + tf)) * 256 + dir * 128 + qc] = v;
  }
}

// ---------------------------------------------------------------------------
// Kernel 3 (fused): wh+ph+feats.  M-tile 64 -> 256 blocks (full-chip).
// ---------------------------------------------------------------------------
__global__ __launch_bounds__(256) void wh_feats_k(
    const unsigned short* __restrict__ wo,   // [NPOS][256] bf16
    const float* __restrict__ whW, const float* __restrict__ whb,
    const float* __restrict__ po,  const float* __restrict__ phW,
    const float* __restrict__ phb, const float* __restrict__ tagW,
    const float* __restrict__ tagb, float* __restrict__ feats) {
  __shared__ unsigned short Ast[2][64 * 32];     // 4KB x2, 16B-slot ^ (row&3)
  __shared__ unsigned short whs[64 * 128];       // 16KB wh tile bf16, swizzled
  __shared__ float tagWs[6 * 136], tagbs[6], phWs[128], phbs[8], whbs[128];
  const int m0  = blockIdx.x * 64;
  const int tid = threadIdx.x;
  const int w   = tid >> 6;
  const int lane = tid & 63;
  const int l15 = lane & 15, lg = lane >> 4;

  for (int i = tid; i < 816; i += 256) tagWs[i] = tagW[i];
  if (tid < 6)   tagbs[tid] = tagb[tid];
  if (tid < 128) phWs[tid]  = phW[tid];
  if (tid < 8)   phbs[tid]  = phb[tid];
  if (tid < 128) whbs[tid]  = whb[tid];

  // B-frags: whW rows n = w*32 + nt*16 + l15, k = kf*32 + lg*8 + e
  short8 bfr[2][8];
  #pragma unroll
  for (int nt = 0; nt < 2; ++nt) {
    const int n = w * 32 + nt * 16 + l15;
    #pragma unroll
    for (int kf = 0; kf < 8; ++kf) {
      const float* p = whW + (long)n * 256 + kf * 32 + lg * 8;
      const float4 f0 = *(const float4*)p;
      const float4 f1 = *(const float4*)(p + 4);
      union { unsigned short u[8]; short8 v; } t;
      t.u[0]=f2bf(f0.x); t.u[1]=f2bf(f0.y); t.u[2]=f2bf(f0.z); t.u[3]=f2bf(f0.w);
      t.u[4]=f2bf(f1.x); t.u[5]=f2bf(f1.y); t.u[6]=f2bf(f1.z); t.u[7]=f2bf(f1.w);
      bfr[nt][kf] = t.v;
    }
  }

  // stage K-chunk kc (32 k) of A (64 rows) into Ast[pb]: one call, 256 thr.
  auto stageA = [&](int kc, int pb) {
    const int row  = tid >> 2;                 // 0..63
    const int slot = tid & 3;
    const unsigned short* gp =
        wo + (long)(m0 + row) * 256 + kc * 32 + ((slot ^ (row & 3)) << 3);
    unsigned short* lb = &Ast[pb][(tid & ~63) << 3];   // wave-uniform base
    gload_lds16(gp, lb);
  };

  f32x4 acc[4][2];
  #pragma unroll
  for (int mt = 0; mt < 4; ++mt)
    #pragma unroll
    for (int nt = 0; nt < 2; ++nt) acc[mt][nt] = (f32x4){0.f,0.f,0.f,0.f};

  stageA(0, 0);
  asm volatile("s_waitcnt vmcnt(0)" ::: "memory");
  __syncthreads();
  for (int kc = 0; kc < 8; ++kc) {
    if (kc < 7) stageA(kc + 1, (kc + 1) & 1);
    const unsigned short* ab = &Ast[kc & 1][0];
    #pragma unroll
    for (int mt = 0; mt < 4; ++mt) {
      const int row = mt * 16 + l15;
      const short8 af = *(const short8*)(ab + row * 32 + ((lg ^ (row & 3)) << 3));
      #pragma unroll
      for (int nt = 0; nt < 2; ++nt)
        acc[mt][nt] = __builtin_amdgcn_mfma_f32_16x16x32_bf16(af, bfr[nt][kc], acc[mt][nt], 0, 0, 0);
    }
    if (kc < 7) {
      asm volatile("s_waitcnt vmcnt(0)" ::: "memory");
      __syncthreads();
    }
  }
  // epilogue 1: relu(wh)+bias -> whs (bf16, 8-ushort slot ^ (row&7))
  #pragma unroll
  for (int nt = 0; nt < 2; ++nt) {
    const int col = w * 32 + nt * 16 + l15;
    const float bv = whbs[col];
    #pragma unroll
    for (int mt = 0; mt < 4; ++mt) {
      #pragma unroll
      for (int r = 0; r < 4; ++r) {
        const int row = mt * 16 + lg * 4 + r;
        const int cs = col ^ ((row & 7) << 3);
        whs[row * 128 + cs] = f2bf(fmaxf(acc[mt][nt][r] + bv, 0.f));
      }
    }
  }
  __syncthreads();
  // epilogue 2: feats. 4 threads per row: row = tid>>2, kq = tid&3.
  {
    const int row = tid >> 2, kq = tid & 3;
    float f[6] = {0.f, 0.f, 0.f, 0.f, 0.f, 0.f};
    #pragma unroll
    for (int ks = 0; ks < 4; ++ks) {             // 4 slots of 8 cols per quarter
      const int k0 = kq * 32 + ks * 8;
      const int slot = (k0 >> 3) ^ (row & 7);
      const short8 v8 = *(const short8*)&whs[row * 128 + slot * 8];
      #pragma unroll
      for (int e = 0; e < 8; ++e) {
        const float wv = bf2f(((unsigned short)v8[e]));
        #pragma unroll
        for (int o = 0; o < 6; ++o) f[o] += wv * tagWs[o * 136 + k0 + e];
      }
    }
    if (kq == 3) {   // this quarter also does the ph part
      const float* pr = po + (long)(m0 + row) * 16;
      float pv[16];
      #pragma unroll
      for (int i = 0; i < 16; i += 4) {
        const float4 v = *(const float4*)(pr + i);
        pv[i] = v.x; pv[i+1] = v.y; pv[i+2] = v.z; pv[i+3] = v.w;
      }
      #pragma unroll
      for (int o8 = 0; o8 < 8; ++o8) {
        float a = phbs[o8];
        #pragma unroll
        for (int k = 0; k < 16; ++k) a += pv[k] * phWs[o8 * 16 + k];
        a = fmaxf(a, 0.f);
        #pragma unroll
        for (int o = 0; o < 6; ++o) f[o] += a * tagWs[o * 136 + 128 + o8];
      }
    }
    #pragma unroll
    for (int o = 0; o < 6; ++o) {
      f[o] += __shfl_xor(f[o], 1);
      f[o] += __shfl_xor(f[o], 2);
    }
    if (kq == 0) {
      #pragma unroll
      for (int o = 0; o < 6; ++o)
        feats[(long)(m0 + row) * 6 + o] = fmaxf(f[o] + tagbs[o], 0.f);
    }
  }
}

// ---------------------------------------------------------------------------
// Kernel 4: CRF NLL. One block, 512 threads: 8 lanes per batch element.
// ---------------------------------------------------------------------------
__global__ __launch_bounds__(512) void crf_k(
    const int* __restrict__ words, const int* __restrict__ labels,
    const float* __restrict__ feats, const float* __restrict__ trans,
    float* __restrict__ out) {
  __shared__ float tn_s[36];
  __shared__ float tE_s[6];
  __shared__ float res_s[64];
  const int tid = threadIdx.x;
  if (tid < 36) {
    const int nx = tid / 6, pv = tid % 6;
    float mx = -1e30f;
    for (int q = 0; q < 6; ++q) mx = fmaxf(mx, trans[q * 6 + pv]);
    float s = 0.f;
    for (int q = 0; q < 6; ++q) s += __expf(trans[q * 6 + pv] - mx);
    tn_s[tid] = (pv == 4) ? -100.f : (__expf(trans[nx * 6 + pv] - mx) / s);
  }
  if (tid < 6) tE_s[tid] = trans[4 * 6 + tid];
  __syncthreads();

  const int lane = tid & 63;
  const int wv   = tid >> 6;
  const int sub  = lane & 7;
  const int b    = wv * 8 + (lane >> 3);

  int cnt = 0;
  for (int t = sub; t < T_; t += 8) cnt += (words[b * T_ + t] != 0) ? 1 : 0;
  cnt += __shfl_xor(cnt, 1); cnt += __shfl_xor(cnt, 2); cnt += __shfl_xor(cnt, 4);
  const int len = cnt;

  float tnr[6];
  #pragma unroll
  for (int p = 0; p < 6; ++p) tnr[p] = (sub < 6) ? tn_s[sub * 6 + p] : -100.f;
  float alpha = (sub == 3) ? 0.f : -100.f;
  for (int t = 0; t < T_; ++t) {
    float ap[6];
    #pragma unroll
    for (int p = 0; p < 6; ++p) ap[p] = __shfl(alpha, p, 8) + tnr[p];
    const float feat = (sub < 6) ? feats[(long)(b * T_ + t) * 6 + sub] : 0.f;
    float m = ap[0];
    #pragma unroll
    for (int p = 1; p < 6; ++p) m = fmaxf(m, ap[p]);
    float s = 0.f;
    #pragma unroll
    for (int p = 0; p < 6; ++p) s += __expf(ap[p] - m);
    const float anew = m + __logf(s) + feat;
    alpha = (t < len) ? anew : alpha;
  }
  float v = (sub < 6) ? (alpha + tE_s[sub]) : -1e30f;
  float m2 = v;
  m2 = fmaxf(m2, __shfl_xor(m2, 1));
  m2 = fmaxf(m2, __shfl_xor(m2, 2));
  m2 = fmaxf(m2, __shfl_xor(m2, 4));
  float e = (sub < 6) ? __expf(v - m2) : 0.f;
  e += __shfl_xor(e, 1); e += __shfl_xor(e, 2); e += __shfl_xor(e, 4);
  const float fwd = m2 + __logf(e);

  int fp = T_;
  for (int t = sub; t < T_; t += 8)
    if (labels[b * T_ + t] == 5) fp = min(fp, t);
  fp = min(fp, __shfl_xor(fp, 1));
  fp = min(fp, __shfl_xor(fp, 2));
  fp = min(fp, __shfl_xor(fp, 4));
  float gs = 0.f;
  for (int t = sub; t < T_; t += 8) {
    if (t < fp) {
      const int lab = labels[b * T_ + t];
      const int prv = (t == 0) ? 3 : labels[b * T_ + t - 1];
      gs += feats[(long)(b * T_ + t) * 6 + lab] + tn_s[lab * 6 + prv];
    }
  }
  gs += __shfl_xor(gs, 1); gs += __shfl_xor(gs, 2); gs += __shfl_xor(gs, 4);
  const float gold = gs + trans[4 * 6 + labels[b * T_ + T_ - 1]];
  if (sub == 0) res_s[b] = fwd - gold;
  __syncthreads();
  if (tid == 0) {
    float r = 0.f;
    for (int i = 0; i < 64; ++i) r += res_s[i];
    out[0] = r * (1.0f / 64.0f);
  }
}

// ---------------------------------------------------------------------------
extern "C" void kernel_launch(void* const* d_in, const int* in_sizes, int n_in,
                              void* d_out, int out_size, void* d_ws, size_t ws_size,
                              hipStream_t stream) {
  (void)in_sizes; (void)n_in; (void)out_size; (void)ws_size;
  const int*   words = (const int*)d_in[0];
  const int*   postg = (const int*)d_in[1];
  const int*   labels= (const int*)d_in[2];
  const float* emb_w = (const float*)d_in[3];
  const float* wlfWi = (const float*)d_in[5];
  const float* wlfWh = (const float*)d_in[6];
  const float* wlfb  = (const float*)d_in[7];
  const float* wlbWi = (const float*)d_in[8];
  const float* wlbWh = (const float*)d_in[9];
  const float* wlbb  = (const float*)d_in[10];
  const float* plfWi = (const float*)d_in[11];
  const float* plfWh = (const float*)d_in[12];
  const float* plfb  = (const float*)d_in[13];
  const float* plbWi = (const float*)d_in[14];
  const float* plbWh = (const float*)d_in[15];
  const float* plbb  = (const float*)d_in[16];
  const float* whW   = (const float*)d_in[17];
  const float* whb   = (const float*)d_in[18];
  const float* phW   = (const float*)d_in[19];
  const float* phb   = (const float*)d_in[20];
  const float* tagW  = (const float*)d_in[21];
  const float* tagb  = (const float*)d_in[22];
  const float* trans = (const float*)d_in[23];

  float* ws = (float*)d_ws;
  unsigned short* xg = (unsigned short*)ws;                 // bf16 [2][256][64][512]
  unsigned short* wo = (unsigned short*)(ws + (size_t)NPOS * 1024); // bf16 [NPOS][256]
  float* po = ws + (size_t)NPOS * 1024 + (size_t)NPOS * 256; // fp32 [NPOS][16]
  float* fe = po + (size_t)NPOS * 16;                        // fp32 [NPOS][6]

  hipLaunchKernelGGL(front_k, dim3(128 + 2048), dim3(256), 0, stream,
                     words, emb_w, wlfWi, wlbWi, wlfb, wlbb, xg,
                     postg, plfWi, plfWh, plfb, plbWi, plbWh, plbb, po);
  hipLaunchKernelGGL(word_lstm_mfma3, dim3(128), dim3(512), 0, stream,
                     xg, wlfWh, wlbWh, wo);
  hipLaunchKernelGGL(wh_feats_k, dim3(NPOS / 64), dim3(256), 0, stream,
                     wo, whW, whb, po, phW, phb, tagW, tagb, fe);
  hipLaunchKernelGGL(crf_k, dim3(1), dim3(512), 0, stream,
                     words, labels, fe, trans, (float*)d_out);
}